// Round 13
// baseline (1025.266 us; speedup 1.0000x reference)
//
#include <hip/hip_runtime.h>
#include <float.h>

#define NQ 8
#define NB 8
#define ND 128
#define NT 8192
#define NK 1024
#define TTILE 64
#define NR 32                       // rounds per q: 16 codes per half per round
#define ESTR 136                    // plane row stride in halves (128 + 8 pad)
#define PLANE_HALVES (32 * ESTR)    // 4352 halves = 8704 B per plane
#define TAU 2e-3f                   // refine margin; approx err ~1.5e-4 << TAU/2

typedef _Float16 half8 __attribute__((ext_vector_type(8)));
typedef float f32x4 __attribute__((ext_vector_type(4)));

// numpy pairwise-8 sum of squares over 128 values (np.sum(a*a, -1), n=128):
// products rounded individually, 8 stride-8 accumulators, fixed combine tree.
__device__ __forceinline__ float np_sumsq_strided(const float* a, int stride) {
#pragma clang fp contract(off)
    float r[8];
    #pragma unroll
    for (int j = 0; j < 8; ++j) { float v = a[j * stride]; r[j] = v * v; }
    #pragma unroll
    for (int i = 1; i < 16; ++i) {
        #pragma unroll
        for (int j = 0; j < 8; ++j) {
            float v = a[(i * 8 + j) * stride];
            r[j] = r[j] + v * v;
        }
    }
    return ((r[0] + r[1]) + (r[2] + r[3])) + ((r[4] + r[5]) + (r[6] + r[7]));
}

// kernel 1: codebook squared norms -> ws (numpy-pairwise-exact)
__global__ void e2_kernel(const float* __restrict__ cb, float* __restrict__ e2) {
    int i = blockIdx.x * blockDim.x + threadIdx.x;  // 0..8191
    e2[i] = np_sumsq_strided(cb + (size_t)i * ND, 1);
}

// kernel 2: codebooks -> fp16 hi/lo planes, per-(q,round) staged order.
// Plane block (q,r): [32 rows hi @ ESTR][32 rows lo @ ESTR]; staged row sr maps
// to code (sr>>4)*512 + r*16 + (sr&15)  (16-code chunk per code-half).
__global__ void prep_kernel(const float* __restrict__ cbs, _Float16* __restrict__ planes) {
    int qr = blockIdx.x;            // 0..255 = q*NR + r
    int q = qr >> 5, r = qr & 31;
    int tid = threadIdx.x;
    int sr = tid >> 3, seg = tid & 7;       // 32 rows x 8 threads (16 dims each)
    int gcode = (sr >> 4) * 512 + r * 16 + (sr & 15);
    const float* gs = cbs + ((size_t)q * NK + gcode) * ND + seg * 16;
    _Float16* dh = planes + (size_t)qr * 2 * PLANE_HALVES + sr * ESTR + seg * 16;
    _Float16* dl = dh + PLANE_HALVES;
    #pragma unroll
    for (int u = 0; u < 2; ++u) {
        float4 v0 = *(const float4*)(gs + u * 8);
        float4 v1 = *(const float4*)(gs + u * 8 + 4);
        float vv[8] = {v0.x, v0.y, v0.z, v0.w, v1.x, v1.y, v1.z, v1.w};
        half8 hh, hl;
        #pragma unroll
        for (int j = 0; j < 8; ++j) {
            _Float16 h = (_Float16)vv[j];
            hh[j] = h;
            hl[j] = (_Float16)(vv[j] - (float)h);
        }
        *(half8*)(dh + u * 8) = hh;
        *(half8*)(dl + u * 8) = hl;
    }
}

__global__ __launch_bounds__(256, 3) void rvq_kernel(
    const float* __restrict__ emb, const float* __restrict__ cbs,
    const float* __restrict__ e2ws, const _Float16* __restrict__ planes,
    float* __restrict__ out)
{
    __shared__ float res[ND * TTILE];          // residual, [d][t] (np-bit fp32) 32KB
    __shared__ _Float16 eb[2 * PLANE_HALVES];  // staged hi+lo planes, 17.4KB
    __shared__ float mb1[2][TTILE], mb2[2][TTILE];
    __shared__ int   mi1[2][TTILE];
    __shared__ int   idx_lds[TTILE];
    __shared__ unsigned long long flagmask;
    __shared__ float wbd[4]; __shared__ int wbi[4];

    const int tid  = threadIdx.x;
    const int lane = tid & 63;
    const int wv   = tid >> 6;
    const int tg   = wv >> 1;     // token group: 32 tokens
    const int ch   = wv & 1;      // code half: 512 codes
    const int c16  = lane & 15;
    const int g4   = lane >> 4;

    const int bidx = blockIdx.x;
    const int b  = bidx >> 7;
    const int t0 = (bidx & 127) * TTILE;
    const float* x = emb + (size_t)b * ND * NT + t0;

    // ---- load residual tile (x) into LDS, [d][t] ----
    {
        int d = tid >> 1, toff = (tid & 1) * 32;
        #pragma unroll
        for (int j = 0; j < 8; ++j)
            *(float4*)&res[d * TTILE + toff + j * 4] = *(const float4*)(x + d * NT + toff + j * 4);
    }
    __syncthreads();

    float* out_idx = out;                         // NQ*NB*NT floats (indices as float)
    float* out_qt  = out + (size_t)NQ * NB * NT;  // NB*ND*NT floats

    for (int q = 0; q < NQ; ++q) {
        const float* cb = cbs + (size_t)q * NK * ND;

        // ---- A-fragments (fp16 split of residual) into registers, once per q ----
        half8 aH[2][4], aL[2][4];
        #pragma unroll
        for (int mt = 0; mt < 2; ++mt) {
            int tok = tg * 32 + mt * 16 + c16;
            #pragma unroll
            for (int kk = 0; kk < 4; ++kk) {
                int k0 = kk * 32 + g4 * 8;
                half8 hh, hl;
                #pragma unroll
                for (int j = 0; j < 8; ++j) {
                    float v = res[(k0 + j) * TTILE + tok];
                    _Float16 h = (_Float16)v;
                    hh[j] = h;
                    hl[j] = (_Float16)(v - (float)h);
                }
                aH[mt][kk] = hh; aL[mt][kk] = hl;
            }
        }

        // ---- per-lane top2 state: s = mt*4 + j ----
        float B1[8], B2[8]; int I1[8];
        #pragma unroll
        for (int s = 0; s < 8; ++s) { B1[s] = FLT_MAX; B2[s] = FLT_MAX; I1[s] = 0; }

        for (int r = 0; r < NR; ++r) {
            __syncthreads();   // prev-round eb readers done
            // ---- async-stage both planes: contiguous 17 KiB = 17 x 1KiB chunks ----
            {
                const char* src = (const char*)(planes + (size_t)(q * NR + r) * 2 * PLANE_HALVES);
                for (int c = wv; c < 17; c += 4) {
                    const char* g = src + c * 1024 + (lane << 4);
                    char* l = (char*)eb + c * 1024;  // wave-uniform base; HW adds lane*16
                    __builtin_amdgcn_global_load_lds(
                        (const __attribute__((address_space(1))) unsigned int*)g,
                        (__attribute__((address_space(3))) unsigned int*)l, 16, 0, 0);
                }
            }
            int gk = ch * 512 + r * 16 + c16;
            float e2v = e2ws[q * NK + gk];     // L2-hot scalar; independent of eb
            __syncthreads();   // barrier drain waits vmcnt(0) -> eb ready

            int crow = ch * 16 + c16;
            half8 bH[4], bL[4];
            #pragma unroll
            for (int kk = 0; kk < 4; ++kk) {
                bH[kk] = *(const half8*)&eb[crow * ESTR + kk * 32 + g4 * 8];
                bL[kk] = *(const half8*)&eb[PLANE_HALVES + crow * ESTR + kk * 32 + g4 * 8];
            }

            f32x4 acc0 = {0.f, 0.f, 0.f, 0.f};
            f32x4 acc1 = {0.f, 0.f, 0.f, 0.f};
            #pragma unroll
            for (int kk = 0; kk < 4; ++kk) {   // hi*hi
                acc0 = __builtin_amdgcn_mfma_f32_16x16x32_f16(aH[0][kk], bH[kk], acc0, 0, 0, 0);
                acc1 = __builtin_amdgcn_mfma_f32_16x16x32_f16(aH[1][kk], bH[kk], acc1, 0, 0, 0);
            }
            #pragma unroll
            for (int kk = 0; kk < 4; ++kk) {   // hi*lo
                acc0 = __builtin_amdgcn_mfma_f32_16x16x32_f16(aH[0][kk], bL[kk], acc0, 0, 0, 0);
                acc1 = __builtin_amdgcn_mfma_f32_16x16x32_f16(aH[1][kk], bL[kk], acc1, 0, 0, 0);
            }
            #pragma unroll
            for (int kk = 0; kk < 4; ++kk) {   // lo*hi  (lo*lo dropped: ~2e-5 << TAU)
                acc0 = __builtin_amdgcn_mfma_f32_16x16x32_f16(aL[0][kk], bH[kk], acc0, 0, 0, 0);
                acc1 = __builtin_amdgcn_mfma_f32_16x16x32_f16(aL[1][kk], bH[kk], acc1, 0, 0, 0);
            }
            // rank by (e2 - 2*dot); r2 is per-token-constant (argmin-invariant)
            #pragma unroll
            for (int j = 0; j < 4; ++j) {
                float d0 = fmaf(-2.f, acc0[j], e2v);
                if (d0 < B1[j])      { B2[j] = B1[j]; B1[j] = d0; I1[j] = gk; }
                else if (d0 < B2[j]) { B2[j] = d0; }
                float d1 = fmaf(-2.f, acc1[j], e2v);
                if (d1 < B1[4 + j])      { B2[4 + j] = B1[4 + j]; B1[4 + j] = d1; I1[4 + j] = gk; }
                else if (d1 < B2[4 + j]) { B2[4 + j] = d1; }
            }
        }

        // ---- cross-lane top2 merge over the 16 code-lanes ----
        #pragma unroll
        for (int s = 0; s < 8; ++s) {
            #pragma unroll
            for (int off = 1; off < 16; off <<= 1) {
                float ob1 = __shfl_xor(B1[s], off, 16);
                float ob2 = __shfl_xor(B2[s], off, 16);
                int   oi  = __shfl_xor(I1[s], off, 16);
                if (ob1 < B1[s] || (ob1 == B1[s] && oi < I1[s])) {
                    B2[s] = fminf(B1[s], ob2); B1[s] = ob1; I1[s] = oi;
                } else {
                    B2[s] = fminf(ob1, B2[s]);
                }
            }
        }
        if (c16 == 0) {
            #pragma unroll
            for (int mt = 0; mt < 2; ++mt)
                #pragma unroll
                for (int j = 0; j < 4; ++j) {
                    int tl = tg * 32 + mt * 16 + g4 * 4 + j;
                    int s = mt * 4 + j;
                    mb1[ch][tl] = B1[s]; mb2[ch][tl] = B2[s]; mi1[ch][tl] = I1[s];
                }
        }
        __syncthreads();

        // ---- merge code-halves; flag near-ties ----
        if (tid < TTILE) {
            float b1 = mb1[0][tid], b2 = mb2[0][tid]; int i1 = mi1[0][tid];
            float c1 = mb1[1][tid], c2 = mb2[1][tid]; int j1 = mi1[1][tid];
            if (c1 < b1) { b2 = fminf(b1, c2); b1 = c1; i1 = j1; }   // tie -> ch0 (lower idx)
            else         { b2 = fminf(c1, b2); }
            idx_lds[tid] = i1;
            bool flag = (b2 - b1) < TAU;
            unsigned long long fm = __ballot(flag);
            if (tid == 0) flagmask = fm;
        }
        __syncthreads();

        // ---- exact (numpy-bit) refine for flagged tokens (rare) ----
        unsigned long long mask = flagmask;
        while (mask) {
            int t = __ffsll((long long)mask) - 1; mask &= mask - 1;
            float r2t = np_sumsq_strided(&res[t], TTILE);   // broadcast reads
            float bd = FLT_MAX; int bi = 0;
            #pragma unroll
            for (int c = 0; c < 4; ++c) {
                int k = tid + 256 * c;   // per-thread k ascending
                const float* er = cb + (size_t)k * ND;
                float s = 0.f;
                #pragma unroll 8
                for (int d = 0; d < ND; ++d)
                    s = fmaf(res[d * TTILE + t], er[d], s);   // BLAS/einsum-identical chain
                float dist;
                {
                #pragma clang fp contract(off)
                    dist = (r2t - 2.0f * s) + e2ws[q * NK + k];
                }
                if (dist < bd) { bd = dist; bi = k; }
            }
            #pragma unroll
            for (int off = 32; off >= 1; off >>= 1) {
                float od = __shfl_xor(bd, off);
                int   oi = __shfl_xor(bi, off);
                if (od < bd || (od == bd && oi < bi)) { bd = od; bi = oi; }
            }
            if (lane == 0) { wbd[wv] = bd; wbi[wv] = bi; }
            __syncthreads();
            if (tid == 0) {
                #pragma unroll
                for (int w = 1; w < 4; ++w)
                    if (wbd[w] < bd || (wbd[w] == bd && wbi[w] < bi)) { bd = wbd[w]; bi = wbi[w]; }
                idx_lds[t] = bi;
            }
            __syncthreads();
        }

        // ---- write indices; residual -= codebook[idx] (exact fp32, float4 gather) ----
        if (tid < TTILE)
            out_idx[(size_t)q * NB * NT + (size_t)b * NT + t0 + tid] = (float)idx_lds[tid];
        {
            int t = tid & 63, grp = tid >> 6;
            int ki = idx_lds[t];
            const float* erow = cb + (size_t)ki * ND + grp * 32;
            #pragma unroll
            for (int j = 0; j < 8; ++j) {
                float4 v = *(const float4*)(erow + j * 4);
                float vv[4] = {v.x, v.y, v.z, v.w};
                #pragma unroll
                for (int u = 0; u < 4; ++u) {
                    int d = grp * 32 + j * 4 + u;
                    res[d * TTILE + t] = res[d * TTILE + t] - vv[u];
                }
            }
        }
        __syncthreads();
    }

    // ---- quantized output = x - final residual, layout [B][D][T] ----
    {
        int d = tid >> 1, toff = (tid & 1) * 32;
        float* o = out_qt + (size_t)b * ND * NT + t0;
        #pragma unroll
        for (int j = 0; j < 8; ++j) {
            float4 xv = *(const float4*)(x + d * NT + toff + j * 4);
            float4 rv = *(const float4*)&res[d * TTILE + toff + j * 4];
            float4 ov = {xv.x - rv.x, xv.y - rv.y, xv.z - rv.z, xv.w - rv.w};
            *(float4*)(o + d * NT + toff + j * 4) = ov;
        }
    }
}

extern "C" void kernel_launch(void* const* d_in, const int* in_sizes, int n_in,
                              void* d_out, int out_size, void* d_ws, size_t ws_size,
                              hipStream_t stream) {
    const float* emb = (const float*)d_in[0];   // [8,128,8192]
    const float* cbs = (const float*)d_in[1];   // [8,1024,128]
    float* out = (float*)d_out;
    float* e2ws = (float*)d_ws;                                 // 8192 floats
    _Float16* planes = (_Float16*)((char*)d_ws + 32768);        // ~4.46 MB staged planes

    e2_kernel<<<NQ * NK / 256, 256, 0, stream>>>(cbs, e2ws);
    prep_kernel<<<NQ * NR, 256, 0, stream>>>(cbs, planes);
    rvq_kernel<<<NB * NT / TTILE, 256, 0, stream>>>(emb, cbs, e2ws, planes, out);
}